// Round 1
// baseline (146.474 us; speedup 1.0000x reference)
//
#include <hip/hip_runtime.h>

#define BLOCK 256
#define RPT 4
#define NROWS (16L*512L*512L)

__device__ __forceinline__ float ex2(float x){ return __builtin_amdgcn_exp2f(x); }
__device__ __forceinline__ float rcp_(float x){ return __builtin_amdgcn_rcpf(x); }
__device__ __forceinline__ float rsq_(float x){ return __builtin_amdgcn_rsqf(x); }

// exact-GELU via Abramowitz-Stegun 7.1.26 erf (|eps| <= 1.5e-7):
// gelu(v) = 0.5*(v + |v|*erfabs(|v|/sqrt2))
__device__ __forceinline__ float gelu_exact(float v){
    float av = fabsf(v);
    float e  = ex2(v*v * -0.7213475204444817f);          // exp(-v^2/2)
    float t  = rcp_(fmaf(0.23164190157f, av, 1.0f));     // 1/(1+0.3275911*|v|/sqrt2)
    float p  = fmaf(fmaf(fmaf(fmaf(1.061405429f, t, -1.453152027f), t,
                              1.421413741f), t, -0.284496736f), t, 0.254829592f);
    p *= t;
    float erfabs = fmaf(-p, e, 1.0f);
    return 0.5f * fmaf(av, erfabs, v);
}

__global__ __launch_bounds__(BLOCK) void nn_kernel(
    const float* __restrict__ feat,
    const float* __restrict__ W0, const float* __restrict__ b0v,
    const float* __restrict__ g0v, const float* __restrict__ be0v,
    const float* __restrict__ W1, const float* __restrict__ b1v,
    const float* __restrict__ g1v, const float* __restrict__ be1v,
    const float* __restrict__ W2, const float* __restrict__ b2v,
    const float* __restrict__ g2v, const float* __restrict__ be2v,
    const float* __restrict__ Wo, const float* __restrict__ bov,
    float* __restrict__ out)
{
    __shared__ __align__(16) float w0t[16*8];    // w0t[j][i] = W0[i][j]
    __shared__ __align__(16) float w1t[16*16];
    __shared__ __align__(16) float w2t[16*16];
    __shared__ __align__(16) float wot[4*16];    // wot[e][i] = Wo[i][e]
    __shared__ float sb[3][16];
    __shared__ float sg[3][16];
    __shared__ float sbe[3][16];
    __shared__ float sbo[4];

    const int tid = threadIdx.x;
    if (tid < 128){ int i = tid >> 4, j = tid & 15; w0t[j*8 + i] = W0[tid]; }
    { int i = tid >> 4, j = tid & 15; w1t[j*16 + i] = W1[tid]; w2t[j*16 + i] = W2[tid]; }
    if (tid < 64){ int i = tid >> 2, e = tid & 3; wot[e*16 + i] = Wo[tid]; }
    if (tid < 16){
        sb[0][tid]  = b0v[tid];  sb[1][tid]  = b1v[tid];  sb[2][tid]  = b2v[tid];
        sg[0][tid]  = g0v[tid];  sg[1][tid]  = g1v[tid];  sg[2][tid]  = g2v[tid];
        sbe[0][tid] = be0v[tid]; sbe[1][tid] = be1v[tid]; sbe[2][tid] = be2v[tid];
    }
    if (tid < 4) sbo[tid] = bov[tid];
    __syncthreads();

    const int base = blockIdx.x * (BLOCK*RPT) + tid;
    const float4* __restrict__ f4 = (const float4*)feat;

    float x[RPT][16];
    float h[RPT][16];

    // ---- load features (8 per row) ----
    float in0[RPT][8];
    #pragma unroll
    for (int r = 0; r < RPT; ++r){
        int row = base + r*BLOCK;
        float4 a = f4[row*2 + 0];
        float4 c = f4[row*2 + 1];
        in0[r][0]=a.x; in0[r][1]=a.y; in0[r][2]=a.z; in0[r][3]=a.w;
        in0[r][4]=c.x; in0[r][5]=c.y; in0[r][6]=c.z; in0[r][7]=c.w;
    }

    // ---- layer 0 (8 -> 16) ----
    #pragma unroll
    for (int j = 0; j < 16; ++j){
        const float4 wa = *(const float4*)&w0t[j*8];
        const float4 wb = *(const float4*)&w0t[j*8 + 4];
        const float bj = sb[0][j];
        #pragma unroll
        for (int r = 0; r < RPT; ++r){
            float acc = bj;
            acc = fmaf(in0[r][0], wa.x, acc);
            acc = fmaf(in0[r][1], wa.y, acc);
            acc = fmaf(in0[r][2], wa.z, acc);
            acc = fmaf(in0[r][3], wa.w, acc);
            acc = fmaf(in0[r][4], wb.x, acc);
            acc = fmaf(in0[r][5], wb.y, acc);
            acc = fmaf(in0[r][6], wb.z, acc);
            acc = fmaf(in0[r][7], wb.w, acc);
            h[r][j] = acc;
        }
    }

    auto ln_gelu = [&](float (&hh)[RPT][16], float (&xx)[RPT][16], int l){
        float nmr[RPT], rs[RPT];
        #pragma unroll
        for (int r = 0; r < RPT; ++r){
            float s = 0.f, s2 = 0.f;
            #pragma unroll
            for (int j = 0; j < 16; ++j){ s += hh[r][j]; s2 = fmaf(hh[r][j], hh[r][j], s2); }
            float mu  = s * 0.0625f;
            float var = fmaf(-mu, mu, s2 * 0.0625f);
            float rsv = rsq_(var + 1e-5f);
            rs[r] = rsv; nmr[r] = -mu * rsv;
        }
        #pragma unroll
        for (int j = 0; j < 16; ++j){
            float gj = sg[l][j], bj = sbe[l][j];
            #pragma unroll
            for (int r = 0; r < RPT; ++r){
                float t = fmaf(hh[r][j], rs[r], nmr[r]);
                xx[r][j] = gelu_exact(fmaf(t, gj, bj));
            }
        }
    };

    auto dense16 = [&](const float* wt, const float* bias,
                       float (&xx)[RPT][16], float (&hh)[RPT][16]){
        #pragma unroll
        for (int j = 0; j < 16; ++j){
            const float4* wr = (const float4*)&wt[j*16];
            float4 a0 = wr[0], a1 = wr[1], a2 = wr[2], a3 = wr[3];
            float wv[16] = {a0.x,a0.y,a0.z,a0.w, a1.x,a1.y,a1.z,a1.w,
                            a2.x,a2.y,a2.z,a2.w, a3.x,a3.y,a3.z,a3.w};
            const float bj = bias[j];
            #pragma unroll
            for (int r = 0; r < RPT; ++r){
                float acc = bj;
                #pragma unroll
                for (int i = 0; i < 16; ++i) acc = fmaf(xx[r][i], wv[i], acc);
                hh[r][j] = acc;
            }
        }
    };

    ln_gelu(h, x, 0);
    dense16(w1t, sb[1], x, h);
    ln_gelu(h, x, 1);
    dense16(w2t, sb[2], x, h);
    ln_gelu(h, x, 2);

    // ---- output layer (16 -> 4), f_a = 1 + tanh(z) = 2 - 2/(exp(2z)+1) ----
    float ov[RPT][4];
    #pragma unroll
    for (int e = 0; e < 4; ++e){
        const float4* wr = (const float4*)&wot[e*16];
        float4 a0 = wr[0], a1 = wr[1], a2 = wr[2], a3 = wr[3];
        float wv[16] = {a0.x,a0.y,a0.z,a0.w, a1.x,a1.y,a1.z,a1.w,
                        a2.x,a2.y,a2.z,a2.w, a3.x,a3.y,a3.z,a3.w};
        const float bj = sbo[e];
        #pragma unroll
        for (int r = 0; r < RPT; ++r){
            float z = bj;
            #pragma unroll
            for (int i = 0; i < 16; ++i) z = fmaf(x[r][i], wv[i], z);
            float q = ex2(z * 2.8853900817779268f);      // e^{2z}
            ov[r][e] = fmaf(-2.0f, rcp_(q + 1.0f), 2.0f);
        }
    }

    float4* __restrict__ o4 = (float4*)out;
    #pragma unroll
    for (int r = 0; r < RPT; ++r){
        o4[base + r*BLOCK] = make_float4(ov[r][0], ov[r][1], ov[r][2], ov[r][3]);
    }
}

extern "C" void kernel_launch(void* const* d_in, const int* in_sizes, int n_in,
                              void* d_out, int out_size, void* d_ws, size_t ws_size,
                              hipStream_t stream) {
    const float* feat = (const float*)d_in[0];
    const float* W0  = (const float*)d_in[1];
    const float* b0  = (const float*)d_in[2];
    const float* g0  = (const float*)d_in[3];
    const float* be0 = (const float*)d_in[4];
    const float* W1  = (const float*)d_in[5];
    const float* b1  = (const float*)d_in[6];
    const float* g1  = (const float*)d_in[7];
    const float* be1 = (const float*)d_in[8];
    const float* W2  = (const float*)d_in[9];
    const float* b2  = (const float*)d_in[10];
    const float* g2  = (const float*)d_in[11];
    const float* be2 = (const float*)d_in[12];
    const float* Wo  = (const float*)d_in[13];
    const float* bo  = (const float*)d_in[14];
    float* out = (float*)d_out;

    const int nblocks = (int)(NROWS / (BLOCK*RPT));   // 4096, exact cover
    hipLaunchKernelGGL(nn_kernel, dim3(nblocks), dim3(BLOCK), 0, stream,
                       feat, W0, b0, g0, be0, W1, b1, g1, be1,
                       W2, b2, g2, be2, Wo, bo, out);
}

// Round 3
// 123.883 us; speedup vs baseline: 1.1824x; 1.1824x over previous
//
#include <hip/hip_runtime.h>

#define BLOCK 256
#define WAVES_PER_BLOCK 4
#define NBLOCKS 1024
#define TILES_PER_WAVE 32
#define NROWS (16L*512L*512L)

typedef __fp16 f16;
typedef f16 f16x2 __attribute__((ext_vector_type(2)));
typedef f16 f16x8 __attribute__((ext_vector_type(8)));
typedef float f32x16 __attribute__((ext_vector_type(16)));

__device__ __forceinline__ float ex2(float x){ return __builtin_amdgcn_exp2f(x); }
__device__ __forceinline__ float rcp_(float x){ return __builtin_amdgcn_rcpf(x); }
__device__ __forceinline__ float rsq_(float x){ return __builtin_amdgcn_rsqf(x); }

__device__ __forceinline__ unsigned pk2(float a, float b){
    f16x2 h = __builtin_amdgcn_cvt_pkrtz(a, b);
    union { f16x2 h; unsigned u; } cv; cv.h = h; return cv.u;
}

// exact-GELU (A&S 7.1.26 erf, |eps|<=1.5e-7) — table build only
__device__ __forceinline__ float gelu_ref(float v){
    float av = fabsf(v);
    float e  = ex2(v*v * -0.7213475204444817f);
    float t  = rcp_(fmaf(0.23164190157f, av, 1.0f));
    float p  = fmaf(fmaf(fmaf(fmaf(1.061405429f, t, -1.453152027f), t,
                              1.421413741f), t, -0.284496736f), t, 0.254829592f);
    p *= t;
    float erfabs = fmaf(-p, e, 1.0f);
    return 0.5f * fmaf(av, erfabs, v);
}

union U8 { f16x8 v; unsigned u[4]; };

__global__ __launch_bounds__(BLOCK) void nn_kernel(
    const float* __restrict__ feat,
    const float* __restrict__ W0, const float* __restrict__ b0v,
    const float* __restrict__ g0v, const float* __restrict__ be0v,
    const float* __restrict__ W1, const float* __restrict__ b1v,
    const float* __restrict__ g1v, const float* __restrict__ be1v,
    const float* __restrict__ W2, const float* __restrict__ b2v,
    const float* __restrict__ g2v, const float* __restrict__ be2v,
    const float* __restrict__ Wo, const float* __restrict__ bov,
    float* __restrict__ out)
{
    __shared__ __align__(16) float tabG[4096];
    __shared__ __align__(16) float cb[3][16];
    __shared__ __align__(16) float cg[3][16];
    __shared__ __align__(16) float cbe[3][16];
    __shared__ __align__(16) float cbo[4];

    const int tid = threadIdx.x;
    if (tid < 16){
        cb[0][tid]  = b0v[tid];  cb[1][tid]  = b1v[tid];  cb[2][tid]  = b2v[tid];
        cg[0][tid]  = g0v[tid];  cg[1][tid]  = g1v[tid];  cg[2][tid]  = g2v[tid];
        cbe[0][tid] = be0v[tid]; cbe[1][tid] = be1v[tid]; cbe[2][tid] = be2v[tid];
    }
    if (tid < 4) cbo[tid] = bov[tid];
    for (int i = tid; i < 4096; i += BLOCK){
        float v = (float)(i - 2048) * (1.0f/512.0f) + (0.5f/512.0f);
        tabG[i] = gelu_ref(v);
    }
    __syncthreads();

    const int lane = tid & 63;
    const int wv   = tid >> 6;
    const int gg   = lane >> 5;      // k-group / n-group selector
    const int c    = lane & 31;      // row index within tile (B col / A row)

    // ---- weight A-fragments: A[n][k] = W[k][n], lane: a[j]=A[c][gg*8+j] ----
    U8 aW0, aW1, aW2, aWo;
    {
        float w[8];
        #pragma unroll
        for (int j=0;j<8;++j) w[j] = (gg==0 && c<16) ? W0[j*16 + c] : 0.f;
        aW0.u[0]=pk2(w[0],w[1]); aW0.u[1]=pk2(w[2],w[3]);
        aW0.u[2]=pk2(w[4],w[5]); aW0.u[3]=pk2(w[6],w[7]);
        #pragma unroll
        for (int j=0;j<8;++j) w[j] = (c<16) ? W1[(gg*8+j)*16 + c] : 0.f;
        aW1.u[0]=pk2(w[0],w[1]); aW1.u[1]=pk2(w[2],w[3]);
        aW1.u[2]=pk2(w[4],w[5]); aW1.u[3]=pk2(w[6],w[7]);
        #pragma unroll
        for (int j=0;j<8;++j) w[j] = (c<16) ? W2[(gg*8+j)*16 + c] : 0.f;
        aW2.u[0]=pk2(w[0],w[1]); aW2.u[1]=pk2(w[2],w[3]);
        aW2.u[2]=pk2(w[4],w[5]); aW2.u[3]=pk2(w[6],w[7]);
        #pragma unroll
        for (int j=0;j<8;++j) w[j] = (c<4) ? Wo[(gg*8+j)*4 + c] : 0.f;
        aWo.u[0]=pk2(w[0],w[1]); aWo.u[1]=pk2(w[2],w[3]);
        aWo.u[2]=pk2(w[4],w[5]); aWo.u[3]=pk2(w[6],w[7]);
    }

    // ---- wave-uniform "gamma==1 && beta==0" fast-path flag ----
    bool okl = true;
    if (lane < 16){
        #pragma unroll
        for (int l=0;l<3;++l)
            okl = okl && (cg[l][lane]==1.0f) && (cbe[l][lane]==0.0f);
    }
    const bool triv = (__ballot(okl) == 0xFFFFFFFFFFFFFFFFull);

    // ---- hoisted per-lane constants ----
    const int n0 = 4*gg, n1 = 8 + 4*gg;
    const float4 b0q0 = *(const float4*)&cb[0][n0], b0q1 = *(const float4*)&cb[0][n1];
    const float4 b1q0 = *(const float4*)&cb[1][n0], b1q1 = *(const float4*)&cb[1][n1];
    const float4 b2q0 = *(const float4*)&cb[2][n0], b2q1 = *(const float4*)&cb[2][n1];
    const float4 gq0s[3] = { *(const float4*)&cg[0][n0], *(const float4*)&cg[1][n0], *(const float4*)&cg[2][n0] };
    const float4 gq1s[3] = { *(const float4*)&cg[0][n1], *(const float4*)&cg[1][n1], *(const float4*)&cg[2][n1] };
    const float4 eq0s[3] = { *(const float4*)&cbe[0][n0], *(const float4*)&cbe[1][n0], *(const float4*)&cbe[2][n0] };
    const float4 eq1s[3] = { *(const float4*)&cbe[0][n1], *(const float4*)&cbe[1][n1], *(const float4*)&cbe[2][n1] };
    float4 oq = make_float4(0.f,0.f,0.f,0.f);
    if (gg==0) oq = *(const float4*)&cbo[0];

    const long gw = (long)blockIdx.x * WAVES_PER_BLOCK + wv;
    const float4* __restrict__ f4 = (const float4*)feat;
    float4* __restrict__ o4 = (float4*)out;

    f32x16 acc;
    #pragma unroll
    for (int i=0;i<16;++i) acc[i]=0.f;

    for (int it = 0; it < TILES_PER_WAVE; ++it){
        const long ri = (gw * TILES_PER_WAVE + it) * 32L + c;

        // ---- layer-0 B-fragment: b[j]=feat[row c][gg*8+j] (k>=8 padded 0) ----
        U8 B;
        if (gg==0){
            float4 u0 = f4[2*ri], u1 = f4[2*ri+1];
            B.u[0]=pk2(u0.x,u0.y); B.u[1]=pk2(u0.z,u0.w);
            B.u[2]=pk2(u1.x,u1.y); B.u[3]=pk2(u1.z,u1.w);
        } else {
            B.u[0]=0u; B.u[1]=0u; B.u[2]=0u; B.u[3]=0u;
        }

        // C-init with layer-0 bias (regs 8..15 never read: A rows >=16 are 0)
        acc[0]=b0q0.x; acc[1]=b0q0.y; acc[2]=b0q0.z; acc[3]=b0q0.w;
        acc[4]=b0q1.x; acc[5]=b0q1.y; acc[6]=b0q1.z; acc[7]=b0q1.w;
        acc = __builtin_amdgcn_mfma_f32_32x32x16_f16(aW0.v, B.v, acc, 0,0,0);

        #pragma unroll
        for (int l = 0; l < 3; ++l){
            // valid h values: acc[0..3] -> n=4gg+i, acc[4..7] -> n=8+4gg+i (bias already in C)
            float hv[8];
            #pragma unroll
            for (int i=0;i<8;++i) hv[i] = acc[i];

            float s = 0.f, s2 = 0.f;
            #pragma unroll
            for (int i=0;i<8;++i){ s += hv[i]; s2 = fmaf(hv[i], hv[i], s2); }
            s  += __shfl_xor(s, 32, 64);
            s2 += __shfl_xor(s2, 32, 64);
            const float mu  = s * 0.0625f;
            const float var = fmaf(-mu, mu, s2 * 0.0625f);
            const float rs  = rsq_(var + 1e-5f);
            const float nm  = -mu * rs;

            float y[8];
            if (triv){
                #pragma unroll
                for (int i=0;i<8;++i){
                    float t  = fmaf(hv[i], rs, nm);
                    float xf = fminf(fmaxf(fmaf(t, 512.f, 2048.f), 0.f), 4095.f);
                    y[i] = tabG[(int)xf];
                }
            } else {
                const float4 gq0 = gq0s[l], gq1 = gq1s[l], eq0 = eq0s[l], eq1 = eq1s[l];
                const float ga[8] = {gq0.x,gq0.y,gq0.z,gq0.w, gq1.x,gq1.y,gq1.z,gq1.w};
                const float ba[8] = {eq0.x,eq0.y,eq0.z,eq0.w, eq1.x,eq1.y,eq1.z,eq1.w};
                #pragma unroll
                for (int i=0;i<8;++i){
                    float t  = fmaf(hv[i], rs, nm);
                    t = fmaf(t, ga[i], ba[i]);
                    float xf = fminf(fmaxf(fmaf(t, 512.f, 2048.f), 0.f), 4095.f);
                    y[i] = tabG[(int)xf];
                }
            }

            // pack + cross-half swap -> next-layer B-fragment
            unsigned P0 = pk2(y[0],y[1]), P1 = pk2(y[2],y[3]);
            unsigned P2 = pk2(y[4],y[5]), P3 = pk2(y[6],y[7]);
            unsigned Q0 = (unsigned)__shfl_xor((int)P0, 32, 64);
            unsigned Q1 = (unsigned)__shfl_xor((int)P1, 32, 64);
            unsigned Q2 = (unsigned)__shfl_xor((int)P2, 32, 64);
            unsigned Q3 = (unsigned)__shfl_xor((int)P3, 32, 64);
            U8 F;
            F.u[0] = gg ? Q2 : P0;
            F.u[1] = gg ? Q3 : P1;
            F.u[2] = gg ? P2 : Q0;
            F.u[3] = gg ? P3 : Q1;

            // C-init with next layer's bias
            if (l == 0){
                acc[0]=b1q0.x; acc[1]=b1q0.y; acc[2]=b1q0.z; acc[3]=b1q0.w;
                acc[4]=b1q1.x; acc[5]=b1q1.y; acc[6]=b1q1.z; acc[7]=b1q1.w;
                acc = __builtin_amdgcn_mfma_f32_32x32x16_f16(aW1.v, F.v, acc, 0,0,0);
            } else if (l == 1){
                acc[0]=b2q0.x; acc[1]=b2q0.y; acc[2]=b2q0.z; acc[3]=b2q0.w;
                acc[4]=b2q1.x; acc[5]=b2q1.y; acc[6]=b2q1.z; acc[7]=b2q1.w;
                acc = __builtin_amdgcn_mfma_f32_32x32x16_f16(aW2.v, F.v, acc, 0,0,0);
            } else {
                acc[0]=oq.x; acc[1]=oq.y; acc[2]=oq.z; acc[3]=oq.w;
                acc[4]=0.f;  acc[5]=0.f;  acc[6]=0.f;  acc[7]=0.f;
                acc = __builtin_amdgcn_mfma_f32_32x32x16_f16(aWo.v, F.v, acc, 0,0,0);
            }
        }

        // ---- output: gg==0 lanes hold energies n=0..3 of row c ----
        if (gg == 0){
            float4 r;
            r.x = fmaf(-2.0f, rcp_(ex2(acc[0]*2.8853900817779268f)+1.0f), 2.0f);
            r.y = fmaf(-2.0f, rcp_(ex2(acc[1]*2.8853900817779268f)+1.0f), 2.0f);
            r.z = fmaf(-2.0f, rcp_(ex2(acc[2]*2.8853900817779268f)+1.0f), 2.0f);
            r.w = fmaf(-2.0f, rcp_(ex2(acc[3]*2.8853900817779268f)+1.0f), 2.0f);
            o4[ri] = r;
        }
    }
}

extern "C" void kernel_launch(void* const* d_in, const int* in_sizes, int n_in,
                              void* d_out, int out_size, void* d_ws, size_t ws_size,
                              hipStream_t stream) {
    const float* feat = (const float*)d_in[0];
    const float* W0  = (const float*)d_in[1];
    const float* b0  = (const float*)d_in[2];
    const float* g0  = (const float*)d_in[3];
    const float* be0 = (const float*)d_in[4];
    const float* W1  = (const float*)d_in[5];
    const float* b1  = (const float*)d_in[6];
    const float* g1  = (const float*)d_in[7];
    const float* be1 = (const float*)d_in[8];
    const float* W2  = (const float*)d_in[9];
    const float* b2  = (const float*)d_in[10];
    const float* g2  = (const float*)d_in[11];
    const float* be2 = (const float*)d_in[12];
    const float* Wo  = (const float*)d_in[13];
    const float* bo  = (const float*)d_in[14];
    float* out = (float*)d_out;

    hipLaunchKernelGGL(nn_kernel, dim3(NBLOCKS), dim3(BLOCK), 0, stream,
                       feat, W0, b0, g0, be0, W1, b1, g1, be1,
                       W2, b2, g2, be2, Wo, bo, out);
}